// Round 11
// baseline (346.150 us; speedup 1.0000x reference)
//
#include <hip/hip_runtime.h>

#define NPTS   16384
#define KCODES 8192
#define DDIM   256
#define HWSZ   1024
#define CHW    (DDIM * HWSZ)          // 262144
#define OUT_ELEMS 4194304
#define LOSS_OFF  OUT_ELEMS
#define IDX_OFF   (OUT_ELEMS + 1)

#define PTB    64                // points per block (2 pt-groups x 32)
#define NTILE  64                // code tiles of 128
#define IMG_US 16384             // ushorts per image: hi[128][64] + lo[128][64]
#define IMG_B  32768
#define SE_OFF_B (256 * IMG_B)   // 8 MB of images, then se[8192] f32

typedef _Float16 half_t;
typedef __attribute__((ext_vector_type(8)))  _Float16 half8;
typedef __attribute__((ext_vector_type(16))) float    v16f;

union HU { _Float16 h; unsigned short u; };

#define GLD16(gp, lp) __builtin_amdgcn_global_load_lds( \
    (const __attribute__((address_space(1))) unsigned int*)(gp), \
    (__attribute__((address_space(3))) unsigned int*)(lp), 16, 0, 0)

// ws images: img = (c>>7)*4 + (k>>6). Row r=c&127 holds its 64 k f16 with
// 16B-block swizzle blk^(r&7)  ->  LDS B-frag reads are 2-way/phase (free),
// DMA staging is pure linear 1KB blocks. lo part at +8192 ushorts.
// Split formulas BIT-IDENTICAL to R7/R9 (proven absmax 0).
__global__ void prep_kernel(const float* __restrict__ emb,
                            unsigned short* __restrict__ eimg,
                            float* __restrict__ se)
{
    const int gw   = (blockIdx.x * 256 + threadIdx.x) >> 6;   // 0..1023
    const int lane = threadIdx.x & 63;
    for (int i = 0; i < 8; ++i) {
        const int c = gw * 8 + i;                             // code 0..8191
        const float4 v = *(const float4*)(emb + (size_t)c * DDIM + lane * 4);
        float ps = v.x * v.x;
        ps = fmaf(v.y, v.y, ps); ps = fmaf(v.z, v.z, ps); ps = fmaf(v.w, v.w, ps);
        float tot = ps;
        #pragma unroll
        for (int off = 1; off < 64; off <<= 1) tot += __shfl_xor(tot, off);
        if (lane == 0) se[c] = tot;
        const float E0 = v.x * 64.f, E1 = v.y * 64.f, E2 = v.z * 64.f, E3 = v.w * 64.f;
        const half_t h0 = (half_t)E0, h1 = (half_t)E1, h2 = (half_t)E2, h3 = (half_t)E3;
        const half_t l0 = (half_t)((E0 - (float)h0) * 2048.f);
        const half_t l1 = (half_t)((E1 - (float)h1) * 2048.f);
        const half_t l2 = (half_t)((E2 - (float)h2) * 2048.f);
        const half_t l3 = (half_t)((E3 - (float)h3) * 2048.f);
        HU uha, uhb, uhc, uhd, ula, ulb, ulc, uld;
        uha.h = h0; uhb.h = h1; uhc.h = h2; uhd.h = h3;
        ula.h = l0; ulb.h = l1; ulc.h = l2; uld.h = l3;
        const unsigned int wh0 = (unsigned)uha.u | ((unsigned)uhb.u << 16);
        const unsigned int wh1 = (unsigned)uhc.u | ((unsigned)uhd.u << 16);
        const unsigned int wl0 = (unsigned)ula.u | ((unsigned)ulb.u << 16);
        const unsigned int wl1 = (unsigned)ulc.u | ((unsigned)uld.u << 16);
        const int kl  = lane * 4;                 // k 0..255
        const int img = (c >> 7) * 4 + (kl >> 6);
        const int k64 = kl & 63;
        const int r   = c & 127;
        const int blk = (k64 >> 3) ^ (r & 7);     // swizzled 16B block
        const size_t base = (size_t)img * IMG_US + r * 64 + blk * 8 + (k64 & 7);
        *(unsigned int*)&eimg[base]            = wh0;
        *(unsigned int*)&eimg[base + 2]        = wh1;
        *(unsigned int*)&eimg[base + 8192]     = wl0;
        *(unsigned int*)&eimg[base + 8192 + 2] = wl1;
    }
}

// m = xh.eh + (xh.el + xl.eh)*2^-11, all via 32x32x16 f16 MFMA; x fragments
// resident in 128 VGPRs (A never touches LDS). dist = fl(fl(s+se) - 2m) fp32,
// lowest-index tie-break (proven R1-R9).
// NOTE: never pass a second __launch_bounds__ arg on this toolchain (R4).
__launch_bounds__(512)
__global__ void vq_kernel(const float* __restrict__ x,
                          const unsigned short* __restrict__ eimg,
                          const float* __restrict__ wse,
                          const float* __restrict__ emb,
                          float* __restrict__ out)
{
    __shared__ __align__(16) unsigned short ldsE[2][IMG_US];  // 65536 B dbuf
    __shared__ float  ldsS[PTB];
    __shared__ float  ldsFD[8][32];
    __shared__ int    ldsFI[8][32];
    __shared__ int    ldsI[PTB];
    __shared__ double ldsL[8];

    const int t    = threadIdx.x;
    const int lane = t & 63;
    const int w    = t >> 6;          // 0..7
    const int pg   = w >> 2;          // pt-group (0,1)
    const int cg   = w & 3;           // code-group (0..3)
    const int n0   = blockIdx.x * PTB;
    const int b    = n0 / HWSZ;
    const int hw0  = n0 % HWSZ;
    const float* xs = x + (size_t)b * CHW + hw0;   // xs[c*HWSZ + p]

    // ---- DMA staging: whole 32KB image; wave w covers bytes [w*4096, +4096) ----
    #define STAGE(img, buf) do { \
        const char* _g = (const char*)eimg + (size_t)(img) * IMG_B + w * 4096 + lane * 16; \
        char* _l = (char*)ldsE[buf] + w * 4096; \
        GLD16(_g,        _l); \
        GLD16(_g + 1024, _l + 1024); \
        GLD16(_g + 2048, _l + 2048); \
        GLD16(_g + 3072, _l + 3072); \
    } while (0)

    STAGE(0, 0);   // bootstrap (drained by prologue barrier)

    // ---- prologue: x -> registers (A-frag layout: row=lane&31, k=(lane>>5)*8+j) ----
    const int prow  = pg * 32 + (lane & 31);
    const int khalf = (lane >> 5) * 8;
    const float* xp = xs + prow;
    half8 xh[16], xl[16];
    float sq = 0.f;
    #pragma unroll
    for (int xc = 0; xc < 16; ++xc) {
        #pragma unroll
        for (int j = 0; j < 8; ++j) {
            const int c = xc * 16 + khalf + j;
            const float v = xp[(size_t)c * HWSZ];
            const half_t hh = (half_t)v;
            const half_t hl = (half_t)((v - (float)hh) * 2048.0f);
            xh[xc][j] = hh;
            xl[xc][j] = hl;
            sq = fmaf(v, v, sq);
        }
    }
    const float s_p = sq + __shfl_xor(sq, 32);     // full ||x_p||^2 (order-invariant for argmin)
    if ((w == 0 || w == 4) && (lane & 63) < 32) ldsS[pg * 32 + lane] = s_p;
    __syncthreads();                               // ldsS visible; image 0 drained

    float s_frag[16];
    #pragma unroll
    for (int q = 0; q < 16; ++q) {
        const int rl = (q & 3) + 8 * (q >> 2) + 4 * (lane >> 5);
        s_frag[q] = ldsS[pg * 32 + rl];
    }

    float best_d[16]; int best_i[16];
    #pragma unroll
    for (int q = 0; q < 16; ++q) { best_d[q] = 3.4e38f; best_i[q] = 0; }

    const int rr  = cg * 32 + (lane & 31);         // B row within 128-code tile
    const int rb7 = rr & 7;
    float se_reg = 0.f;
    v16f acc_hh, acc_hl;

    for (int tile = 0; tile < NTILE; ++tile) {
        #pragma unroll
        for (int q = 0; q < 16; ++q) { acc_hh[q] = 0.f; acc_hl[q] = 0.f; }
        #pragma unroll
        for (int kc = 0; kc < 4; ++kc) {
            const int buf = kc & 1;                // image idx = tile*4+kc == kc (mod 2)
            __syncthreads();                       // drain DMA for buf; readers of other buf done
            {
                int nimg = tile * 4 + kc + 1;
                if (nimg == 256) nimg = 0;         // harmless dummy
                STAGE(nimg, (kc + 1) & 1);         // async under compute
            }
            if (kc == 2) se_reg = wse[tile * 128 + rr];
            #pragma unroll
            for (int s = 0; s < 4; ++s) {
                const int bblk = (s * 2 + (lane >> 5)) ^ rb7;
                const unsigned short* bp = &ldsE[buf][rr * 64 + bblk * 8];
                const half8 bh = *(const half8*)bp;
                const half8 bl = *(const half8*)(bp + 8192);
                const int xc = kc * 4 + s;         // compile-time (both loops unrolled)
                acc_hh = __builtin_amdgcn_mfma_f32_32x32x16_f16(xh[xc], bh, acc_hh, 0, 0, 0);
                acc_hl = __builtin_amdgcn_mfma_f32_32x32x16_f16(xh[xc], bl, acc_hl, 0, 0, 0);
                acc_hl = __builtin_amdgcn_mfma_f32_32x32x16_f16(xl[xc], bh, acc_hl, 0, 0, 0);
            }
        }
        // ---- tile finalize: dist = fl(fl(s+se) - 2m); col (code) fixed per lane ----
        const int code = tile * 128 + rr;
        #pragma unroll
        for (int q = 0; q < 16; ++q) {
            const float m = fmaf(acc_hl[q], 4.8828125e-4f, acc_hh[q]) * 0.015625f;
            const float T = s_frag[q] + se_reg;
            const float d = fmaf(-2.0f, m, T);
            if (d < best_d[q]) { best_d[q] = d; best_i[q] = code; }
        }
    }

    // ---- argmin: butterfly over 32 cols (lexicographic), per 32-lane half ----
    #pragma unroll
    for (int off = 1; off < 32; off <<= 1) {
        #pragma unroll
        for (int q = 0; q < 16; ++q) {
            const float d2 = __shfl_xor(best_d[q], off);
            const int   i2 = __shfl_xor(best_i[q], off);
            if (d2 < best_d[q] || (d2 == best_d[q] && i2 < best_i[q])) {
                best_d[q] = d2; best_i[q] = i2;
            }
        }
    }
    if ((lane & 31) == 0) {
        #pragma unroll
        for (int q = 0; q < 16; ++q) {
            const int rl = (q & 3) + 8 * (q >> 2) + 4 * (lane >> 5);
            ldsFD[w][rl] = best_d[q];
            ldsFI[w][rl] = best_i[q];
        }
    }
    __syncthreads();
    if (t < PTB) {
        const int pg2 = t >> 5, rl = t & 31;
        float bd = ldsFD[pg2 * 4][rl];
        int   bi = ldsFI[pg2 * 4][rl];
        #pragma unroll
        for (int c2 = 1; c2 < 4; ++c2) {
            const float d2 = ldsFD[pg2 * 4 + c2][rl];
            const int   i2 = ldsFI[pg2 * 4 + c2][rl];
            if (d2 < bd || (d2 == bd && i2 < bi)) { bd = d2; bi = i2; }
        }
        ldsI[t] = bi;
        out[(size_t)IDX_OFF + n0 + t] = (float)bi;
    }
    __syncthreads();

    // ---- epilogue: gather e row, straight-through out, loss partial ----
    double lsum = 0.0;
    {
        const int p  = t & 63;
        const int cgp = t >> 6;
        const int row = ldsI[p];
        const float* erow = emb + (size_t)row * DDIM;
        float* ob = out + (size_t)b * CHW + hw0 + p;
        for (int q = 0; q < 32; ++q) {
            const int c = cgp * 32 + q;
            const float e  = erow[c];
            const float xx = xs[(size_t)c * HWSZ + p];
            const float diff = e - xx;             // fl(x_q - xt)
            ob[(size_t)c * HWSZ] = xx + diff;      // straight-through rounding
            lsum += (double)diff * (double)diff;
        }
    }
    #pragma unroll
    for (int off = 32; off > 0; off >>= 1)
        lsum += __shfl_xor(lsum, off);
    if ((t & 63) == 0) ldsL[t >> 6] = lsum;
    __syncthreads();
    if (t == 0) {
        double tot = 0.0;
        #pragma unroll
        for (int wv = 0; wv < 8; ++wv) tot += ldsL[wv];
        atomicAdd(&out[LOSS_OFF], (float)(tot * (1.25 / 4194304.0)));
    }
}

extern "C" void kernel_launch(void* const* d_in, const int* in_sizes, int n_in,
                              void* d_out, int out_size, void* d_ws, size_t ws_size,
                              hipStream_t stream) {
    (void)in_sizes; (void)n_in; (void)out_size; (void)ws_size;
    const float* x   = (const float*)d_in[0];
    const float* emb = (const float*)d_in[1];
    float* out = (float*)d_out;
    unsigned short* eimg = (unsigned short*)d_ws;
    float*          wse  = (float*)((char*)d_ws + SE_OFF_B);
    (void)hipMemsetAsync((char*)d_out + (size_t)LOSS_OFF * sizeof(float), 0, sizeof(float), stream);
    prep_kernel<<<256, 256, 0, stream>>>(emb, eimg, wse);
    vq_kernel<<<NPTS / PTB, 512, 0, stream>>>(x, eimg, wse, emb, out);
}